// Round 7
// baseline (340.474 us; speedup 1.0000x reference)
//
#include <hip/hip_runtime.h>
#include <math.h>

#define NN 100000
#define NE 1600000
#define F_IN 128
#define HID 64
#define OUTF 40
#define NB 391      // (NN+255)/256
#define NPART 8     // node partitions, one per XCD (blockIdx%8 heuristic)
#define PSIZE 12500 // NN / NPART exactly
#define BCAP 210000 // bucket capacity (expected 200K +- 0.4K)

typedef unsigned short u16;

__device__ __forceinline__ float bf2f(u16 u) {
    return __uint_as_float(((unsigned int)u) << 16);
}
__device__ __forceinline__ u16 f2bf(float f) {  // RNE
    unsigned int x = __float_as_uint(f);
    return (u16)((x + 0x7fffu + ((x >> 16) & 1u)) >> 16);
}

// ---------------- CSR build ----------------
__global__ void k_zero(int* deg, int* bcnt) {
    int i = blockIdx.x * blockDim.x + threadIdx.x;
    if (i < NN) deg[i] = 0;
    if (i < NPART) bcnt[i] = 0;
}

// Bucket edges by destination partition. One read of the edge list; chunky
// reserved-range writes (R6: streaming re-reads were evicting dirty L2 lines,
// 68MB HBM write for 6.4MB eidx -- buckets make hist/fill fully L2-local).
__launch_bounds__(256)
__global__ void k_bucket(const int* __restrict__ ei, int* __restrict__ bcnt,
                         int2* __restrict__ bkt) {
    __shared__ int cnt[NPART], base[NPART], cur[NPART];
    int t = threadIdx.x;
    int tile0 = blockIdx.x * 2048;
    if (t < NPART) cnt[t] = 0;
    __syncthreads();
    int rows[8], cols[8];
#pragma unroll
    for (int i = 0; i < 8; i++) {
        int e = tile0 + i * 256 + t;
        if (e < NE) {
            rows[i] = __builtin_nontemporal_load(&ei[e]);
            int c = __builtin_nontemporal_load(&ei[NE + e]);
            cols[i] = c;
            atomicAdd(&cnt[c / PSIZE], 1);
        } else cols[i] = -1;
    }
    __syncthreads();
    if (t < NPART) { base[t] = atomicAdd(&bcnt[t], cnt[t]); cur[t] = 0; }
    __syncthreads();
#pragma unroll
    for (int i = 0; i < 8; i++) {
        if (cols[i] >= 0) {
            int b = cols[i] / PSIZE;
            int pos = base[b] + atomicAdd(&cur[b], 1);
            bkt[(size_t)b * BCAP + pos] = make_int2(rows[i], cols[i]);
        }
    }
}

// Partition-local histogram from bucket p: 1.6MB stream + 50KB deg slice both
// fit one XCD's 4MB L2.
__global__ void k_hist_b(const int* __restrict__ bcnt, const int2* __restrict__ bkt,
                         int* __restrict__ deg) {
    int p = blockIdx.x & (NPART - 1);
    int n = bcnt[p];
    const int2* bp = bkt + (size_t)p * BCAP;
    int tid = (blockIdx.x >> 3) * blockDim.x + threadIdx.x;
    int stride = (gridDim.x >> 3) * blockDim.x;
    for (int i = tid; i < n; i += stride)
        atomicAdd(&deg[bp[i].y], 1);
}

__global__ void k_dinv(const int* __restrict__ deg, float* __restrict__ dinv) {
    int i = blockIdx.x * blockDim.x + threadIdx.x;
    if (i < NN) dinv[i] = rsqrtf((float)(deg[i] + 1));  // +1 self-loop
}

__global__ void k_blocksum(const int* __restrict__ deg, int* __restrict__ bsum) {
    __shared__ int s[256];
    int t = threadIdx.x;
    int i = blockIdx.x * 256 + t;
    s[t] = (i < NN) ? deg[i] : 0;
    __syncthreads();
    for (int o = 128; o > 0; o >>= 1) {
        if (t < o) s[t] += s[t + o];
        __syncthreads();
    }
    if (t == 0) bsum[blockIdx.x] = s[0];
}

__global__ void k_scanbsum(int* __restrict__ bsum) {  // 1 block, 512 threads
    __shared__ int s[512];
    int t = threadIdx.x;
    int v = (t < NB) ? bsum[t] : 0;
    s[t] = v;
    __syncthreads();
    for (int o = 1; o < 512; o <<= 1) {
        int add = (t >= o) ? s[t - o] : 0;
        __syncthreads();
        s[t] += add;
        __syncthreads();
    }
    if (t < NB) bsum[t] = s[t] - v;  // exclusive
}

__global__ void k_cursor(const int* __restrict__ deg, const int* __restrict__ bsum,
                         int* __restrict__ cursor) {
    __shared__ int s[256];
    int t = threadIdx.x;
    int i = blockIdx.x * 256 + t;
    int v = (i < NN) ? deg[i] : 0;
    s[t] = v;
    __syncthreads();
    for (int o = 1; o < 256; o <<= 1) {
        int add = (t >= o) ? s[t - o] : 0;
        __syncthreads();
        s[t] += add;
        __syncthreads();
    }
    if (i < NN) cursor[i] = bsum[blockIdx.x] + s[t] - v;  // exclusive prefix
}

// Partition-local fill from bucket p: 1.6MB stream + 800KB eidx slice + 50KB
// cursor all L2-resident -> each eidx line written back once.
__global__ void k_fill_b(const int* __restrict__ bcnt, const int2* __restrict__ bkt,
                         int* __restrict__ cursor, int* __restrict__ eidx) {
    int p = blockIdx.x & (NPART - 1);
    int n = bcnt[p];
    const int2* bp = bkt + (size_t)p * BCAP;
    int tid = (blockIdx.x >> 3) * blockDim.x + threadIdx.x;
    int stride = (gridDim.x >> 3) * blockDim.x;
    for (int i = tid; i < n; i += stride) {
        int2 rc = bp[i];
        int pos = atomicAdd(&cursor[rc.y], 1);
        eidx[pos] = rc.x;
    }
    // after: cursor[n] == rowoff[n+1]
}

// ---------------- GEMM1: h1 = bf16(x @ W1) ----------------
__launch_bounds__(256)
__global__ void k_gemm1(const float* __restrict__ x, const float* __restrict__ W1,
                        u16* __restrict__ h1) {
    __shared__ float Xs[64][132];
    __shared__ float Ws[128][64];
    int t = threadIdx.x;
    int row0 = blockIdx.x * 64;

#pragma unroll
    for (int i = 0; i < 8; i++) {
        int idx4 = t + 256 * i;
        float4 v = ((const float4*)W1)[idx4];
        int k = idx4 >> 4;
        int c4 = (idx4 & 15) << 2;
        *(float4*)&Ws[k][c4] = v;
    }
#pragma unroll
    for (int i = 0; i < 8; i++) {
        int idx4 = t + 256 * i;
        int r = idx4 >> 5;
        int k4 = (idx4 & 31) << 2;
        int gr = row0 + r;
        if (gr >= NN) gr = NN - 1;
        float4 v = *(const float4*)&x[gr * F_IN + k4];
        *(float4*)&Xs[r][k4] = v;
    }
    __syncthreads();

    int tx = t & 15, ty = t >> 4;
    int cb = tx << 2, rb = ty << 2;
    float acc[4][4] = {};
#pragma unroll 2   // capped: full unroll spills (R1)
    for (int k = 0; k < F_IN; k += 4) {
        float4 xv[4], wv[4];
#pragma unroll
        for (int i = 0; i < 4; i++) xv[i] = *(const float4*)&Xs[rb + i][k];
#pragma unroll
        for (int kk = 0; kk < 4; kk++) wv[kk] = *(const float4*)&Ws[k + kk][cb];
#pragma unroll
        for (int i = 0; i < 4; i++) {
            const float* xp = (const float*)&xv[i];
#pragma unroll
            for (int kk = 0; kk < 4; kk++) {
                acc[i][0] += xp[kk] * wv[kk].x;
                acc[i][1] += xp[kk] * wv[kk].y;
                acc[i][2] += xp[kk] * wv[kk].z;
                acc[i][3] += xp[kk] * wv[kk].w;
            }
        }
    }
#pragma unroll
    for (int i = 0; i < 4; i++) {
        int gr = row0 + rb + i;
        if (gr < NN) {
            ushort4 o;
            o.x = f2bf(acc[i][0]); o.y = f2bf(acc[i][1]);
            o.z = f2bf(acc[i][2]); o.w = f2bf(acc[i][3]);
            *(ushort4*)&h1[(size_t)gr * HID + cb] = o;
        }
    }
}

// ---------------- aggregation: bf16 rows, 4 edge-groups x 16 lanes ----------------
template <bool RELU_BIAS, bool OUT_BF16>
__global__ void k_agg(const int* __restrict__ cursor, const int* __restrict__ eidx,
                      const float* __restrict__ dinv, const u16* __restrict__ h,
                      const float* __restrict__ bias, void* __restrict__ outp) {
    int lane = threadIdx.x & 63;
    int n = (blockIdx.x * blockDim.x + threadIdx.x) >> 6;
    if (n >= NN) return;
    int eg = lane >> 4;        // edge group 0..3
    int fq = lane & 15;        // bf16x4 index within 64-elem row
    int end = cursor[n];
    int start = (n == 0) ? 0 : cursor[n - 1];
    float dn = dinv[n];

    float4 acc = make_float4(0.f, 0.f, 0.f, 0.f);
    if (eg == 0) {  // self-loop
        ushort4 hv = *(const ushort4*)&h[(size_t)n * HID + fq * 4];
        float w = dn * dn;
        acc.x += bf2f(hv.x) * w; acc.y += bf2f(hv.y) * w;
        acc.z += bf2f(hv.z) * w; acc.w += bf2f(hv.w) * w;
    }
    float4 acc2 = make_float4(0.f, 0.f, 0.f, 0.f);
    int j = start + eg;
    for (; j + 4 < end; j += 8) {
        int s0 = eidx[j];
        int s1 = eidx[j + 4];
        float w0 = dinv[s0] * dn;
        float w1 = dinv[s1] * dn;
        ushort4 a = *(const ushort4*)&h[(size_t)s0 * HID + fq * 4];
        ushort4 b = *(const ushort4*)&h[(size_t)s1 * HID + fq * 4];
        acc.x  += bf2f(a.x) * w0; acc.y  += bf2f(a.y) * w0;
        acc.z  += bf2f(a.z) * w0; acc.w  += bf2f(a.w) * w0;
        acc2.x += bf2f(b.x) * w1; acc2.y += bf2f(b.y) * w1;
        acc2.z += bf2f(b.z) * w1; acc2.w += bf2f(b.w) * w1;
    }
    if (j < end) {
        int s0 = eidx[j];
        float w0 = dinv[s0] * dn;
        ushort4 a = *(const ushort4*)&h[(size_t)s0 * HID + fq * 4];
        acc.x += bf2f(a.x) * w0; acc.y += bf2f(a.y) * w0;
        acc.z += bf2f(a.z) * w0; acc.w += bf2f(a.w) * w0;
    }
    acc.x += acc2.x; acc.y += acc2.y; acc.z += acc2.z; acc.w += acc2.w;

#pragma unroll
    for (int o = 16; o <= 32; o <<= 1) {
        acc.x += __shfl_xor(acc.x, o, 64);
        acc.y += __shfl_xor(acc.y, o, 64);
        acc.z += __shfl_xor(acc.z, o, 64);
        acc.w += __shfl_xor(acc.w, o, 64);
    }
    if (eg == 0) {
        if (RELU_BIAS) {
            float4 bb = *(const float4*)&bias[fq * 4];
            acc.x = fmaxf(acc.x + bb.x, 0.f);
            acc.y = fmaxf(acc.y + bb.y, 0.f);
            acc.z = fmaxf(acc.z + bb.z, 0.f);
            acc.w = fmaxf(acc.w + bb.w, 0.f);
        }
        if (OUT_BF16) {
            ushort4 o;
            o.x = f2bf(acc.x); o.y = f2bf(acc.y);
            o.z = f2bf(acc.z); o.w = f2bf(acc.w);
            *(ushort4*)((u16*)outp + (size_t)n * HID + fq * 4) = o;
        } else {
            *(float4*)((float*)outp + (size_t)n * HID + fq * 4) = acc;
        }
    }
}

// ---------------- GEMM2: out = s @ W2 + b2 ----------------
__launch_bounds__(320)
__global__ void k_gemm2(const float* __restrict__ s_in, const float* __restrict__ W2,
                        const float* __restrict__ b2, float* __restrict__ outb) {
    __shared__ float As[128][68];
    __shared__ float Ws[64][40];
    int t = threadIdx.x;
    int row0 = blockIdx.x * 128;

    for (int i = t; i < 64 * 40; i += 320) Ws[i / 40][i % 40] = W2[i];

    for (int idx4 = t; idx4 < 2048; idx4 += 320) {
        int r = idx4 >> 4, k4 = (idx4 & 15) << 2;
        int gr = row0 + r;
        if (gr >= NN) gr = NN - 1;
        *(float4*)&As[r][k4] = *(const float4*)&s_in[(size_t)gr * HID + k4];
    }
    __syncthreads();

    int tx = t % 10, ty = t / 10;
    int cb = tx * 4, rb = ty * 4;
    float acc[4][4] = {};
#pragma unroll 2   // capped: full unroll spills (R1)
    for (int k = 0; k < HID; k += 4) {
        float4 xv[4], wv[4];
#pragma unroll
        for (int i = 0; i < 4; i++) xv[i] = *(const float4*)&As[rb + i][k];
#pragma unroll
        for (int kk = 0; kk < 4; kk++) wv[kk] = *(const float4*)&Ws[k + kk][cb];
#pragma unroll
        for (int i = 0; i < 4; i++) {
            const float* xp = (const float*)&xv[i];
#pragma unroll
            for (int kk = 0; kk < 4; kk++) {
                acc[i][0] += xp[kk] * wv[kk].x;
                acc[i][1] += xp[kk] * wv[kk].y;
                acc[i][2] += xp[kk] * wv[kk].z;
                acc[i][3] += xp[kk] * wv[kk].w;
            }
        }
    }
    float4 bb = *(const float4*)&b2[cb];
#pragma unroll
    for (int i = 0; i < 4; i++) {
        int gr = row0 + rb + i;
        if (gr < NN)
            *(float4*)&outb[(size_t)gr * OUTF + cb] =
                make_float4(acc[i][0] + bb.x, acc[i][1] + bb.y,
                            acc[i][2] + bb.z, acc[i][3] + bb.w);
    }
}

// ---------------- log_softmax in place ----------------
__global__ void k_logsoftmax(float* __restrict__ outb) {
    int lane = threadIdx.x & 63;
    int wid = (blockIdx.x * blockDim.x + threadIdx.x) >> 6;
    if (wid >= NN) return;
    float v = (lane < OUTF) ? outb[(size_t)wid * OUTF + lane] : -INFINITY;
    float m = v;
#pragma unroll
    for (int o = 32; o > 0; o >>= 1) m = fmaxf(m, __shfl_xor(m, o, 64));
    float p = (lane < OUTF) ? __expf(v - m) : 0.f;
    float s = p;
#pragma unroll
    for (int o = 32; o > 0; o >>= 1) s += __shfl_xor(s, o, 64);
    float r = v - m - __logf(s);
    if (lane < OUTF) outb[(size_t)wid * OUTF + lane] = r;
}

extern "C" void kernel_launch(void* const* d_in, const int* in_sizes, int n_in,
                              void* d_out, int out_size, void* d_ws, size_t ws_size,
                              hipStream_t stream) {
    const float* x  = (const float*)d_in[0];
    const int*   ei = (const int*)d_in[1];
    const float* W1 = (const float*)d_in[2];
    const float* b1 = (const float*)d_in[3];
    const float* W2 = (const float*)d_in[4];
    const float* b2 = (const float*)d_in[5];
    float* outb = (float*)d_out;

    // workspace layout (4B word units)
    int*   deg    = (int*)d_ws;                 // 100000
    float* dinv   = (float*)d_ws + 100000;      // 100000
    int*   cursor = (int*)d_ws + 200000;        // 100000
    int*   bsum   = (int*)d_ws + 300000;        // 1024
    int*   bcnt   = (int*)d_ws + 301024;        // 8
    int*   eidx   = (int*)d_ws + 301056;        // 1600000
    u16*   h1     = (u16*)((int*)d_ws + 1901056);   // 6.4M bf16 = 3.2M words
    u16*   r      = (u16*)((int*)d_ws + 5101056);   // 6.4M bf16 = 3.2M words
    float* s      = (float*)d_ws + 8301056;     // 6.4M fp32 words
    int2*  bkt    = (int2*)s;                   // 8*210000*2 words, dead before agg2

    k_zero<<<NB, 256, 0, stream>>>(deg, bcnt);
    k_bucket<<<(NE + 2047) / 2048, 256, 0, stream>>>(ei, bcnt, bkt);
    k_hist_b<<<2048, 256, 0, stream>>>(bcnt, bkt, deg);
    k_dinv<<<NB, 256, 0, stream>>>(deg, dinv);
    k_blocksum<<<NB, 256, 0, stream>>>(deg, bsum);
    k_scanbsum<<<1, 512, 0, stream>>>(bsum);
    k_cursor<<<NB, 256, 0, stream>>>(deg, bsum, cursor);
    k_fill_b<<<2048, 256, 0, stream>>>(bcnt, bkt, cursor, eidx);

    k_gemm1<<<(NN + 63) / 64, 256, 0, stream>>>(x, W1, h1);
    // r = bf16(relu(A @ h1 + b1))
    k_agg<true, true><<<(NN * 64 + 255) / 256, 256, 0, stream>>>(cursor, eidx, dinv, h1, b1, r);
    // s = A @ r (fp32)
    k_agg<false, false><<<(NN * 64 + 255) / 256, 256, 0, stream>>>(cursor, eidx, dinv, r, nullptr, s);
    // out = s @ W2 + b2, then log_softmax
    k_gemm2<<<(NN + 127) / 128, 320, 0, stream>>>(s, W2, b2, outb);
    k_logsoftmax<<<(NN * 64 + 255) / 256, 256, 0, stream>>>(outb);
}

// Round 8
// 231.527 us; speedup vs baseline: 1.4706x; 1.4706x over previous
//
#include <hip/hip_runtime.h>
#include <math.h>

#define NN 100000
#define NE 1600000
#define F_IN 128
#define HID 64
#define OUTF 40
#define NBKT 391     // node buckets of 256 nodes
#define BCAPB 5120   // per-bucket capacity (mean 4096, +16 sigma)
#define TILE 16384   // edges per k_bucket block
#define NTILES 98    // ceil(NE/TILE)

typedef unsigned short u16;

__device__ __forceinline__ float bf2f(u16 u) {
    return __uint_as_float(((unsigned int)u) << 16);
}
__device__ __forceinline__ u16 f2bf(float f) {  // RNE
    unsigned int x = __float_as_uint(f);
    return (u16)((x + 0x7fffu + ((x >> 16) & 1u)) >> 16);
}

// ---------------- CSR build: LDS counting sort ----------------
__global__ void k_zero(int* bcnt) {
    int i = threadIdx.x;
    if (i < NBKT) bcnt[i] = 0;
}

// Tile-wise LDS counting sort into 391 node-range buckets. All global writes
// are contiguous runs (R7: random 4B stores are partial-line writes with NO
// write-allocate -> 65MB HBM for 6.4MB payload; line-granular is the only fix).
__launch_bounds__(512)
__global__ void k_bucket(const int* __restrict__ ei, int* __restrict__ bcnt,
                         int* __restrict__ bkt) {
    __shared__ int hist[NBKT], goff[NBKT], cur[NBKT];
    __shared__ int stage[TILE];
    int t = threadIdx.x;
    int e0 = blockIdx.x * TILE;
    int ecnt = min(TILE, NE - e0);
    for (int i = t; i < NBKT; i += 512) hist[i] = 0;
    __syncthreads();
    // pass 1: histogram of destination buckets
    for (int i = t; i < ecnt; i += 512)
        atomicAdd(&hist[ei[NE + e0 + i] >> 8], 1);
    __syncthreads();
    if (t == 0) {  // serial exclusive scan (391 elems, once per block)
        int run = 0;
        for (int b = 0; b < NBKT; b++) { cur[b] = run; run += hist[b]; }
    }
    __syncthreads();
    for (int b = t; b < NBKT; b += 512)
        goff[b] = atomicAdd(&bcnt[b], hist[b]);
    __syncthreads();
    // pass 2: place packed (col_local<<17 | row) into LDS-sorted stage
    for (int i = t; i < ecnt; i += 512) {
        int c = ei[NE + e0 + i];
        int r = ei[e0 + i];
        int pos = atomicAdd(&cur[c >> 8], 1);
        stage[pos] = ((c & 255) << 17) | r;
    }
    __syncthreads();
    // copy out: contiguous run per bucket (avg ~42 ints)
    int wv = t >> 6, ln = t & 63;
    for (int b = wv; b < NBKT; b += 8) {
        int cnt = hist[b];
        int lo = cur[b] - cnt;
        int gb = b * BCAPB + goff[b];
        for (int i = ln; i < cnt; i += 64)
            bkt[gb + i] = stage[lo + i];
    }
}

__global__ void k_scanb(int* __restrict__ bcnt, int* __restrict__ bboff) {
    __shared__ int s[512];
    int t = threadIdx.x;
    int v = (t < NBKT) ? bcnt[t] : 0;
    s[t] = v;
    __syncthreads();
    for (int o = 1; o < 512; o <<= 1) {
        int add = (t >= o) ? s[t - o] : 0;
        __syncthreads();
        s[t] += add;
        __syncthreads();
    }
    if (t < NBKT) bboff[t] = s[t] - v;  // exclusive
}

// One block per bucket: LDS hist -> dinv + cursor (rowoff ends) + sorted eidx,
// all written as fully-coalesced contiguous runs.
__launch_bounds__(256)
__global__ void k_csr(const int* __restrict__ bcnt, const int* __restrict__ bboff,
                      const int* __restrict__ bkt, float* __restrict__ dinv,
                      int* __restrict__ cursor, int* __restrict__ eidx) {
    __shared__ int hist[256], loff[256], cur[256], sscan[256];
    __shared__ int stage[BCAPB];
    int t = threadIdx.x;
    int b = blockIdx.x;
    int cnt = bcnt[b];
    int base = bboff[b];
    const int* bp = bkt + b * BCAPB;
    hist[t] = 0;
    __syncthreads();
    for (int i = t; i < cnt; i += 256)
        atomicAdd(&hist[bp[i] >> 17], 1);
    __syncthreads();
    int n = b * 256 + t;
    int d = hist[t];
    if (n < NN) dinv[n] = rsqrtf((float)(d + 1));  // +1 self-loop
    sscan[t] = d;
    __syncthreads();
    for (int o = 1; o < 256; o <<= 1) {
        int add = (t >= o) ? sscan[t - o] : 0;
        __syncthreads();
        sscan[t] += add;
        __syncthreads();
    }
    loff[t] = sscan[t] - d;
    cur[t] = 0;
    if (n < NN) cursor[n] = base + sscan[t];  // rowoff[n+1]
    __syncthreads();
    for (int i = t; i < cnt; i += 256) {
        int v = bp[i];
        int pos = loff[v >> 17] + atomicAdd(&cur[v >> 17], 1);
        stage[pos] = v & 0x1FFFF;
    }
    __syncthreads();
    for (int i = t; i < cnt; i += 256)
        eidx[base + i] = stage[i];
}

// ---------------- GEMM1: h1 = bf16(x @ W1) ----------------
__launch_bounds__(256)
__global__ void k_gemm1(const float* __restrict__ x, const float* __restrict__ W1,
                        u16* __restrict__ h1) {
    __shared__ float Xs[64][132];
    __shared__ float Ws[128][64];
    int t = threadIdx.x;
    int row0 = blockIdx.x * 64;

#pragma unroll
    for (int i = 0; i < 8; i++) {
        int idx4 = t + 256 * i;
        float4 v = ((const float4*)W1)[idx4];
        int k = idx4 >> 4;
        int c4 = (idx4 & 15) << 2;
        *(float4*)&Ws[k][c4] = v;
    }
#pragma unroll
    for (int i = 0; i < 8; i++) {
        int idx4 = t + 256 * i;
        int r = idx4 >> 5;
        int k4 = (idx4 & 31) << 2;
        int gr = row0 + r;
        if (gr >= NN) gr = NN - 1;
        float4 v = *(const float4*)&x[gr * F_IN + k4];
        *(float4*)&Xs[r][k4] = v;
    }
    __syncthreads();

    int tx = t & 15, ty = t >> 4;
    int cb = tx << 2, rb = ty << 2;
    float acc[4][4] = {};
#pragma unroll 2   // capped: full unroll spills (R1)
    for (int k = 0; k < F_IN; k += 4) {
        float4 xv[4], wv[4];
#pragma unroll
        for (int i = 0; i < 4; i++) xv[i] = *(const float4*)&Xs[rb + i][k];
#pragma unroll
        for (int kk = 0; kk < 4; kk++) wv[kk] = *(const float4*)&Ws[k + kk][cb];
#pragma unroll
        for (int i = 0; i < 4; i++) {
            const float* xp = (const float*)&xv[i];
#pragma unroll
            for (int kk = 0; kk < 4; kk++) {
                acc[i][0] += xp[kk] * wv[kk].x;
                acc[i][1] += xp[kk] * wv[kk].y;
                acc[i][2] += xp[kk] * wv[kk].z;
                acc[i][3] += xp[kk] * wv[kk].w;
            }
        }
    }
#pragma unroll
    for (int i = 0; i < 4; i++) {
        int gr = row0 + rb + i;
        if (gr < NN) {
            ushort4 o;
            o.x = f2bf(acc[i][0]); o.y = f2bf(acc[i][1]);
            o.z = f2bf(acc[i][2]); o.w = f2bf(acc[i][3]);
            *(ushort4*)&h1[(size_t)gr * HID + cb] = o;
        }
    }
}

// ---------------- aggregation: bf16 rows, 4 edge-groups x 16 lanes ----------------
template <bool RELU_BIAS, bool OUT_BF16>
__global__ void k_agg(const int* __restrict__ cursor, const int* __restrict__ eidx,
                      const float* __restrict__ dinv, const u16* __restrict__ h,
                      const float* __restrict__ bias, void* __restrict__ outp) {
    int lane = threadIdx.x & 63;
    int n = (blockIdx.x * blockDim.x + threadIdx.x) >> 6;
    if (n >= NN) return;
    int eg = lane >> 4;        // edge group 0..3
    int fq = lane & 15;        // bf16x4 index within 64-elem row
    int end = cursor[n];
    int start = (n == 0) ? 0 : cursor[n - 1];
    float dn = dinv[n];

    float4 acc = make_float4(0.f, 0.f, 0.f, 0.f);
    if (eg == 0) {  // self-loop
        ushort4 hv = *(const ushort4*)&h[(size_t)n * HID + fq * 4];
        float w = dn * dn;
        acc.x += bf2f(hv.x) * w; acc.y += bf2f(hv.y) * w;
        acc.z += bf2f(hv.z) * w; acc.w += bf2f(hv.w) * w;
    }
    float4 acc2 = make_float4(0.f, 0.f, 0.f, 0.f);
    int j = start + eg;
    for (; j + 4 < end; j += 8) {
        int s0 = eidx[j];
        int s1 = eidx[j + 4];
        float w0 = dinv[s0] * dn;
        float w1 = dinv[s1] * dn;
        ushort4 a = *(const ushort4*)&h[(size_t)s0 * HID + fq * 4];
        ushort4 b = *(const ushort4*)&h[(size_t)s1 * HID + fq * 4];
        acc.x  += bf2f(a.x) * w0; acc.y  += bf2f(a.y) * w0;
        acc.z  += bf2f(a.z) * w0; acc.w  += bf2f(a.w) * w0;
        acc2.x += bf2f(b.x) * w1; acc2.y += bf2f(b.y) * w1;
        acc2.z += bf2f(b.z) * w1; acc2.w += bf2f(b.w) * w1;
    }
    if (j < end) {
        int s0 = eidx[j];
        float w0 = dinv[s0] * dn;
        ushort4 a = *(const ushort4*)&h[(size_t)s0 * HID + fq * 4];
        acc.x += bf2f(a.x) * w0; acc.y += bf2f(a.y) * w0;
        acc.z += bf2f(a.z) * w0; acc.w += bf2f(a.w) * w0;
    }
    acc.x += acc2.x; acc.y += acc2.y; acc.z += acc2.z; acc.w += acc2.w;

#pragma unroll
    for (int o = 16; o <= 32; o <<= 1) {
        acc.x += __shfl_xor(acc.x, o, 64);
        acc.y += __shfl_xor(acc.y, o, 64);
        acc.z += __shfl_xor(acc.z, o, 64);
        acc.w += __shfl_xor(acc.w, o, 64);
    }
    if (eg == 0) {
        if (RELU_BIAS) {
            float4 bb = *(const float4*)&bias[fq * 4];
            acc.x = fmaxf(acc.x + bb.x, 0.f);
            acc.y = fmaxf(acc.y + bb.y, 0.f);
            acc.z = fmaxf(acc.z + bb.z, 0.f);
            acc.w = fmaxf(acc.w + bb.w, 0.f);
        }
        if (OUT_BF16) {
            ushort4 o;
            o.x = f2bf(acc.x); o.y = f2bf(acc.y);
            o.z = f2bf(acc.z); o.w = f2bf(acc.w);
            *(ushort4*)((u16*)outp + (size_t)n * HID + fq * 4) = o;
        } else {
            *(float4*)((float*)outp + (size_t)n * HID + fq * 4) = acc;
        }
    }
}

// ---------------- GEMM2: out = s @ W2 + b2 ----------------
__launch_bounds__(320)
__global__ void k_gemm2(const float* __restrict__ s_in, const float* __restrict__ W2,
                        const float* __restrict__ b2, float* __restrict__ outb) {
    __shared__ float As[128][68];
    __shared__ float Ws[64][40];
    int t = threadIdx.x;
    int row0 = blockIdx.x * 128;

    for (int i = t; i < 64 * 40; i += 320) Ws[i / 40][i % 40] = W2[i];

    for (int idx4 = t; idx4 < 2048; idx4 += 320) {
        int r = idx4 >> 4, k4 = (idx4 & 15) << 2;
        int gr = row0 + r;
        if (gr >= NN) gr = NN - 1;
        *(float4*)&As[r][k4] = *(const float4*)&s_in[(size_t)gr * HID + k4];
    }
    __syncthreads();

    int tx = t % 10, ty = t / 10;
    int cb = tx * 4, rb = ty * 4;
    float acc[4][4] = {};
#pragma unroll 2   // capped: full unroll spills (R1)
    for (int k = 0; k < HID; k += 4) {
        float4 xv[4], wv[4];
#pragma unroll
        for (int i = 0; i < 4; i++) xv[i] = *(const float4*)&As[rb + i][k];
#pragma unroll
        for (int kk = 0; kk < 4; kk++) wv[kk] = *(const float4*)&Ws[k + kk][cb];
#pragma unroll
        for (int i = 0; i < 4; i++) {
            const float* xp = (const float*)&xv[i];
#pragma unroll
            for (int kk = 0; kk < 4; kk++) {
                acc[i][0] += xp[kk] * wv[kk].x;
                acc[i][1] += xp[kk] * wv[kk].y;
                acc[i][2] += xp[kk] * wv[kk].z;
                acc[i][3] += xp[kk] * wv[kk].w;
            }
        }
    }
    float4 bb = *(const float4*)&b2[cb];
#pragma unroll
    for (int i = 0; i < 4; i++) {
        int gr = row0 + rb + i;
        if (gr < NN)
            *(float4*)&outb[(size_t)gr * OUTF + cb] =
                make_float4(acc[i][0] + bb.x, acc[i][1] + bb.y,
                            acc[i][2] + bb.z, acc[i][3] + bb.w);
    }
}

// ---------------- log_softmax in place ----------------
__global__ void k_logsoftmax(float* __restrict__ outb) {
    int lane = threadIdx.x & 63;
    int wid = (blockIdx.x * blockDim.x + threadIdx.x) >> 6;
    if (wid >= NN) return;
    float v = (lane < OUTF) ? outb[(size_t)wid * OUTF + lane] : -INFINITY;
    float m = v;
#pragma unroll
    for (int o = 32; o > 0; o >>= 1) m = fmaxf(m, __shfl_xor(m, o, 64));
    float p = (lane < OUTF) ? __expf(v - m) : 0.f;
    float s = p;
#pragma unroll
    for (int o = 32; o > 0; o >>= 1) s += __shfl_xor(s, o, 64);
    float r = v - m - __logf(s);
    if (lane < OUTF) outb[(size_t)wid * OUTF + lane] = r;
}

extern "C" void kernel_launch(void* const* d_in, const int* in_sizes, int n_in,
                              void* d_out, int out_size, void* d_ws, size_t ws_size,
                              hipStream_t stream) {
    const float* x  = (const float*)d_in[0];
    const int*   ei = (const int*)d_in[1];
    const float* W1 = (const float*)d_in[2];
    const float* b1 = (const float*)d_in[3];
    const float* W2 = (const float*)d_in[4];
    const float* b2 = (const float*)d_in[5];
    float* outb = (float*)d_out;

    // workspace layout (4B word units)
    float* dinv   = (float*)d_ws;                   // 100000
    int*   cursor = (int*)d_ws + 100000;            // 100000
    int*   bcnt   = (int*)d_ws + 200000;            // 512
    int*   bboff  = (int*)d_ws + 200512;            // 512
    int*   eidx   = (int*)d_ws + 201024;            // 1600000
    u16*   h1     = (u16*)((int*)d_ws + 1801024);   // 6.4M bf16 = 3.2M words
    u16*   r      = (u16*)((int*)d_ws + 5001024);   // 6.4M bf16 = 3.2M words
    float* s      = (float*)d_ws + 8201024;         // 6.4M fp32 words
    int*   bkt    = (int*)s;                        // NBKT*BCAPB = 2.0M words, dead before agg2

    k_zero<<<1, 512, 0, stream>>>(bcnt);
    k_bucket<<<NTILES, 512, 0, stream>>>(ei, bcnt, bkt);
    k_scanb<<<1, 512, 0, stream>>>(bcnt, bboff);
    k_csr<<<NBKT, 256, 0, stream>>>(bcnt, bboff, bkt, dinv, cursor, eidx);

    k_gemm1<<<(NN + 63) / 64, 256, 0, stream>>>(x, W1, h1);
    // r = bf16(relu(A @ h1 + b1))
    k_agg<true, true><<<(NN * 64 + 255) / 256, 256, 0, stream>>>(cursor, eidx, dinv, h1, b1, r);
    // s = A @ r (fp32)
    k_agg<false, false><<<(NN * 64 + 255) / 256, 256, 0, stream>>>(cursor, eidx, dinv, r, nullptr, s);
    // out = s @ W2 + b2, then log_softmax
    k_gemm2<<<(NN + 127) / 128, 320, 0, stream>>>(s, W2, b2, outb);
    k_logsoftmax<<<(NN * 64 + 255) / 256, 256, 0, stream>>>(outb);
}

// Round 9
// 199.922 us; speedup vs baseline: 1.7030x; 1.1581x over previous
//
#include <hip/hip_runtime.h>
#include <math.h>

#define NN 100000
#define NE 1600000
#define F_IN 128
#define HID 64
#define OUTF 40
#define NBKT 391     // node buckets of 256 nodes
#define BCAPB 5120   // per-bucket capacity (mean 4096, +16 sigma)
#define TILE 16384   // edges per k_bucket block
#define NTILES 98    // ceil(NE/TILE)

typedef unsigned short u16;

__device__ __forceinline__ float bf2f(u16 u) {
    return __uint_as_float(((unsigned int)u) << 16);
}
__device__ __forceinline__ u16 f2bf(float f) {  // RNE
    unsigned int x = __float_as_uint(f);
    return (u16)((x + 0x7fffu + ((x >> 16) & 1u)) >> 16);
}

// unpack int4 = 8 bf16, fma into acc[8]
__device__ __forceinline__ void fma8(const int4 v, float w, float* acc) {
    acc[0] += __uint_as_float(((unsigned)v.x) << 16) * w;
    acc[1] += __uint_as_float(v.x & 0xffff0000u) * w;
    acc[2] += __uint_as_float(((unsigned)v.y) << 16) * w;
    acc[3] += __uint_as_float(v.y & 0xffff0000u) * w;
    acc[4] += __uint_as_float(((unsigned)v.z) << 16) * w;
    acc[5] += __uint_as_float(v.z & 0xffff0000u) * w;
    acc[6] += __uint_as_float(((unsigned)v.w) << 16) * w;
    acc[7] += __uint_as_float(v.w & 0xffff0000u) * w;
}

// ---------------- CSR build: LDS counting sort ----------------
__global__ void k_zero(int* bcnt) {
    int i = threadIdx.x;
    if (i < NBKT) bcnt[i] = 0;
}

__launch_bounds__(512)
__global__ void k_bucket(const int* __restrict__ ei, int* __restrict__ bcnt,
                         int* __restrict__ bkt) {
    __shared__ int hist[NBKT], goff[NBKT], cur[NBKT];
    __shared__ int stage[TILE];
    int t = threadIdx.x;
    int e0 = blockIdx.x * TILE;
    int ecnt = min(TILE, NE - e0);
    for (int i = t; i < NBKT; i += 512) hist[i] = 0;
    __syncthreads();
    for (int i = t; i < ecnt; i += 512)
        atomicAdd(&hist[ei[NE + e0 + i] >> 8], 1);
    __syncthreads();
    if (t == 0) {
        int run = 0;
        for (int b = 0; b < NBKT; b++) { cur[b] = run; run += hist[b]; }
    }
    __syncthreads();
    for (int b = t; b < NBKT; b += 512)
        goff[b] = atomicAdd(&bcnt[b], hist[b]);
    __syncthreads();
    for (int i = t; i < ecnt; i += 512) {
        int c = ei[NE + e0 + i];
        int r = ei[e0 + i];
        int pos = atomicAdd(&cur[c >> 8], 1);
        stage[pos] = ((c & 255) << 17) | r;
    }
    __syncthreads();
    int wv = t >> 6, ln = t & 63;
    for (int b = wv; b < NBKT; b += 8) {
        int cnt = hist[b];
        int lo = cur[b] - cnt;
        int gb = b * BCAPB + goff[b];
        for (int i = ln; i < cnt; i += 64)
            bkt[gb + i] = stage[lo + i];
    }
}

__global__ void k_scanb(int* __restrict__ bcnt, int* __restrict__ bboff) {
    __shared__ int s[512];
    int t = threadIdx.x;
    int v = (t < NBKT) ? bcnt[t] : 0;
    s[t] = v;
    __syncthreads();
    for (int o = 1; o < 512; o <<= 1) {
        int add = (t >= o) ? s[t - o] : 0;
        __syncthreads();
        s[t] += add;
        __syncthreads();
    }
    if (t < NBKT) bboff[t] = s[t] - v;  // exclusive
}

__launch_bounds__(256)
__global__ void k_csr(const int* __restrict__ bcnt, const int* __restrict__ bboff,
                      const int* __restrict__ bkt, float* __restrict__ dinv,
                      int* __restrict__ cursor, int* __restrict__ eidx) {
    __shared__ int hist[256], loff[256], cur[256], sscan[256];
    __shared__ int stage[BCAPB];
    int t = threadIdx.x;
    int b = blockIdx.x;
    int cnt = bcnt[b];
    int base = bboff[b];
    const int* bp = bkt + b * BCAPB;
    hist[t] = 0;
    __syncthreads();
    for (int i = t; i < cnt; i += 256)
        atomicAdd(&hist[bp[i] >> 17], 1);
    __syncthreads();
    int n = b * 256 + t;
    int d = hist[t];
    if (n < NN) dinv[n] = rsqrtf((float)(d + 1));  // +1 self-loop
    sscan[t] = d;
    __syncthreads();
    for (int o = 1; o < 256; o <<= 1) {
        int add = (t >= o) ? sscan[t - o] : 0;
        __syncthreads();
        sscan[t] += add;
        __syncthreads();
    }
    loff[t] = sscan[t] - d;
    cur[t] = 0;
    if (n < NN) cursor[n] = base + sscan[t];  // rowoff[n+1]
    __syncthreads();
    for (int i = t; i < cnt; i += 256) {
        int v = bp[i];
        int pos = loff[v >> 17] + atomicAdd(&cur[v >> 17], 1);
        stage[pos] = v & 0x1FFFF;
    }
    __syncthreads();
    for (int i = t; i < cnt; i += 256)
        eidx[base + i] = stage[i];
}

// ---------------- GEMM1: h1 = bf16(x @ W1) ----------------
__launch_bounds__(256)
__global__ void k_gemm1(const float* __restrict__ x, const float* __restrict__ W1,
                        u16* __restrict__ h1) {
    __shared__ float Xs[64][132];
    __shared__ float Ws[128][64];
    int t = threadIdx.x;
    int row0 = blockIdx.x * 64;

#pragma unroll
    for (int i = 0; i < 8; i++) {
        int idx4 = t + 256 * i;
        float4 v = ((const float4*)W1)[idx4];
        int k = idx4 >> 4;
        int c4 = (idx4 & 15) << 2;
        *(float4*)&Ws[k][c4] = v;
    }
#pragma unroll
    for (int i = 0; i < 8; i++) {
        int idx4 = t + 256 * i;
        int r = idx4 >> 5;
        int k4 = (idx4 & 31) << 2;
        int gr = row0 + r;
        if (gr >= NN) gr = NN - 1;
        float4 v = *(const float4*)&x[gr * F_IN + k4];
        *(float4*)&Xs[r][k4] = v;
    }
    __syncthreads();

    int tx = t & 15, ty = t >> 4;
    int cb = tx << 2, rb = ty << 2;
    float acc[4][4] = {};
#pragma unroll 2   // capped: full unroll spills (R1)
    for (int k = 0; k < F_IN; k += 4) {
        float4 xv[4], wv[4];
#pragma unroll
        for (int i = 0; i < 4; i++) xv[i] = *(const float4*)&Xs[rb + i][k];
#pragma unroll
        for (int kk = 0; kk < 4; kk++) wv[kk] = *(const float4*)&Ws[k + kk][cb];
#pragma unroll
        for (int i = 0; i < 4; i++) {
            const float* xp = (const float*)&xv[i];
#pragma unroll
            for (int kk = 0; kk < 4; kk++) {
                acc[i][0] += xp[kk] * wv[kk].x;
                acc[i][1] += xp[kk] * wv[kk].y;
                acc[i][2] += xp[kk] * wv[kk].z;
                acc[i][3] += xp[kk] * wv[kk].w;
            }
        }
    }
#pragma unroll
    for (int i = 0; i < 4; i++) {
        int gr = row0 + rb + i;
        if (gr < NN) {
            ushort4 o;
            o.x = f2bf(acc[i][0]); o.y = f2bf(acc[i][1]);
            o.z = f2bf(acc[i][2]); o.w = f2bf(acc[i][3]);
            *(ushort4*)&h1[(size_t)gr * HID + cb] = o;
        }
    }
}

// ---------------- aggregation: 8 edge-groups x 8 lanes, 16B row loads ----------------
// 16 independent gathers in flight per wave (R8: 4x16 layout had only 8 and
// VALUBusy 42% -> latency-bound).
template <bool RELU_BIAS, bool OUT_BF16>
__global__ void k_agg(const int* __restrict__ cursor, const int* __restrict__ eidx,
                      const float* __restrict__ dinv, const u16* __restrict__ h,
                      const float* __restrict__ bias, void* __restrict__ outp) {
    int lane = threadIdx.x & 63;
    int n = (blockIdx.x * blockDim.x + threadIdx.x) >> 6;
    if (n >= NN) return;
    int eg = lane >> 3;        // edge group 0..7
    int fo = (lane & 7) * 8;   // 8 bf16 per lane
    int end = cursor[n];
    int start = (n == 0) ? 0 : cursor[n - 1];
    float dn = dinv[n];

    float acc[8] = {}, acc2[8] = {};
    if (eg == 0) {  // self-loop
        int4 hv = *(const int4*)&h[(size_t)n * HID + fo];
        fma8(hv, dn * dn, acc);
    }
    int j = start + eg;
    for (; j + 8 < end; j += 16) {
        int s0 = eidx[j];
        int s1 = eidx[j + 8];
        float w0 = dinv[s0] * dn;
        float w1 = dinv[s1] * dn;
        int4 a = *(const int4*)&h[(size_t)s0 * HID + fo];
        int4 b = *(const int4*)&h[(size_t)s1 * HID + fo];
        fma8(a, w0, acc);
        fma8(b, w1, acc2);
    }
    if (j < end) {
        int s0 = eidx[j];
        float w0 = dinv[s0] * dn;
        int4 a = *(const int4*)&h[(size_t)s0 * HID + fo];
        fma8(a, w0, acc);
    }
#pragma unroll
    for (int i = 0; i < 8; i++) acc[i] += acc2[i];

    // reduce across the 8 edge groups (lane bits 3,4,5)
#pragma unroll
    for (int o = 8; o <= 32; o <<= 1) {
#pragma unroll
        for (int i = 0; i < 8; i++) acc[i] += __shfl_xor(acc[i], o, 64);
    }
    if (eg == 0) {
        if (RELU_BIAS) {
#pragma unroll
            for (int i = 0; i < 8; i++)
                acc[i] = fmaxf(acc[i] + bias[fo + i], 0.f);
        }
        if (OUT_BF16) {
            int4 o;
            o.x = (int)f2bf(acc[0]) | ((int)f2bf(acc[1]) << 16);
            o.y = (int)f2bf(acc[2]) | ((int)f2bf(acc[3]) << 16);
            o.z = (int)f2bf(acc[4]) | ((int)f2bf(acc[5]) << 16);
            o.w = (int)f2bf(acc[6]) | ((int)f2bf(acc[7]) << 16);
            *(int4*)((u16*)outp + (size_t)n * HID + fo) = o;
        } else {
            float* op = (float*)outp + (size_t)n * HID + fo;
            *(float4*)op = make_float4(acc[0], acc[1], acc[2], acc[3]);
            *(float4*)(op + 4) = make_float4(acc[4], acc[5], acc[6], acc[7]);
        }
    }
}

// ---------------- GEMM2 + bias + log_softmax fused ----------------
__launch_bounds__(320)
__global__ void k_gemm2(const float* __restrict__ s_in, const float* __restrict__ W2,
                        const float* __restrict__ b2, float* __restrict__ outb) {
    __shared__ float As[128][68];   // staging; later reused as Os[40][132]
    __shared__ float Ws[64][40];
    __shared__ float rowm[128], rowls[128];
    int t = threadIdx.x;
    int row0 = blockIdx.x * 128;

    for (int i = t; i < 64 * 40; i += 320) Ws[i / 40][i % 40] = W2[i];

    for (int idx4 = t; idx4 < 2048; idx4 += 320) {
        int r = idx4 >> 4, k4 = (idx4 & 15) << 2;
        int gr = row0 + r;
        if (gr >= NN) gr = NN - 1;
        *(float4*)&As[r][k4] = *(const float4*)&s_in[(size_t)gr * HID + k4];
    }
    __syncthreads();

    int tx = t % 10, ty = t / 10;
    int cb = tx * 4, rb = ty * 4;
    float acc[4][4] = {};
#pragma unroll 2   // capped: full unroll spills (R1)
    for (int k = 0; k < HID; k += 4) {
        float4 xv[4], wv[4];
#pragma unroll
        for (int i = 0; i < 4; i++) xv[i] = *(const float4*)&As[rb + i][k];
#pragma unroll
        for (int kk = 0; kk < 4; kk++) wv[kk] = *(const float4*)&Ws[k + kk][cb];
#pragma unroll
        for (int i = 0; i < 4; i++) {
            const float* xp = (const float*)&xv[i];
#pragma unroll
            for (int kk = 0; kk < 4; kk++) {
                acc[i][0] += xp[kk] * wv[kk].x;
                acc[i][1] += xp[kk] * wv[kk].y;
                acc[i][2] += xp[kk] * wv[kk].z;
                acc[i][3] += xp[kk] * wv[kk].w;
            }
        }
    }
    float4 bb = *(const float4*)&b2[cb];
#pragma unroll
    for (int i = 0; i < 4; i++) {
        acc[i][0] += bb.x; acc[i][1] += bb.y;
        acc[i][2] += bb.z; acc[i][3] += bb.w;
    }

    // fused log_softmax over the 40 cols of each of the 128 rows
    __syncthreads();  // all As reads done; reuse as Os[40][132]
    float* Os = &As[0][0];
#pragma unroll
    for (int i = 0; i < 4; i++) {
        int row = rb + i;
        Os[(cb + 0) * 132 + row] = acc[i][0];
        Os[(cb + 1) * 132 + row] = acc[i][1];
        Os[(cb + 2) * 132 + row] = acc[i][2];
        Os[(cb + 3) * 132 + row] = acc[i][3];
    }
    __syncthreads();
    if (t < 128) {
        float m = -INFINITY;
        for (int c = 0; c < OUTF; c++) m = fmaxf(m, Os[c * 132 + t]);
        float sum = 0.f;
        for (int c = 0; c < OUTF; c++) sum += __expf(Os[c * 132 + t] - m);
        rowm[t] = m;
        rowls[t] = __logf(sum);
    }
    __syncthreads();
#pragma unroll
    for (int i = 0; i < 4; i++) {
        int row = rb + i;
        int gr = row0 + row;
        if (gr < NN) {
            float sh = rowm[row] + rowls[row];
            *(float4*)&outb[(size_t)gr * OUTF + cb] =
                make_float4(acc[i][0] - sh, acc[i][1] - sh,
                            acc[i][2] - sh, acc[i][3] - sh);
        }
    }
}

extern "C" void kernel_launch(void* const* d_in, const int* in_sizes, int n_in,
                              void* d_out, int out_size, void* d_ws, size_t ws_size,
                              hipStream_t stream) {
    const float* x  = (const float*)d_in[0];
    const int*   ei = (const int*)d_in[1];
    const float* W1 = (const float*)d_in[2];
    const float* b1 = (const float*)d_in[3];
    const float* W2 = (const float*)d_in[4];
    const float* b2 = (const float*)d_in[5];
    float* outb = (float*)d_out;

    // workspace layout (4B word units)
    float* dinv   = (float*)d_ws;                   // 100000
    int*   cursor = (int*)d_ws + 100000;            // 100000
    int*   bcnt   = (int*)d_ws + 200000;            // 512
    int*   bboff  = (int*)d_ws + 200512;            // 512
    int*   eidx   = (int*)d_ws + 201024;            // 1600000
    u16*   h1     = (u16*)((int*)d_ws + 1801024);   // 6.4M bf16 = 3.2M words
    u16*   r      = (u16*)((int*)d_ws + 5001024);   // 6.4M bf16 = 3.2M words
    float* s      = (float*)d_ws + 8201024;         // 6.4M fp32 words
    int*   bkt    = (int*)s;                        // NBKT*BCAPB = 2.0M words, dead before agg2

    k_zero<<<1, 512, 0, stream>>>(bcnt);
    k_bucket<<<NTILES, 512, 0, stream>>>(ei, bcnt, bkt);
    k_scanb<<<1, 512, 0, stream>>>(bcnt, bboff);
    k_csr<<<NBKT, 256, 0, stream>>>(bcnt, bboff, bkt, dinv, cursor, eidx);

    k_gemm1<<<(NN + 63) / 64, 256, 0, stream>>>(x, W1, h1);
    // r = bf16(relu(A @ h1 + b1))
    k_agg<true, true><<<(NN * 64 + 255) / 256, 256, 0, stream>>>(cursor, eidx, dinv, h1, b1, r);
    // s = A @ r (fp32)
    k_agg<false, false><<<(NN * 64 + 255) / 256, 256, 0, stream>>>(cursor, eidx, dinv, r, nullptr, s);
    // out = log_softmax(s @ W2 + b2)
    k_gemm2<<<(NN + 127) / 128, 320, 0, stream>>>(s, W2, b2, outb);
}

// Round 10
// 195.968 us; speedup vs baseline: 1.7374x; 1.0202x over previous
//
#include <hip/hip_runtime.h>
#include <math.h>

#define NN 100000
#define NE 1600000
#define F_IN 128
#define HID 64
#define OUTF 40
#define NBKT 391     // node buckets of 256 nodes
#define BCAPB 5120   // per-bucket capacity (mean 4096, +16 sigma)
#define TILE 16384   // edges per k_bucket block
#define NTILES 98    // ceil(NE/TILE)

typedef unsigned short u16;

__device__ __forceinline__ u16 f2bf(float f) {  // RNE
    unsigned int x = __float_as_uint(f);
    return (u16)((x + 0x7fffu + ((x >> 16) & 1u)) >> 16);
}

// unpack int4 = 8 bf16, add into acc[8] (rows are pre-scaled by dinv -> pure add)
__device__ __forceinline__ void add8(const int4 v, float* acc) {
    acc[0] += __uint_as_float(((unsigned)v.x) << 16);
    acc[1] += __uint_as_float(v.x & 0xffff0000u);
    acc[2] += __uint_as_float(((unsigned)v.y) << 16);
    acc[3] += __uint_as_float(v.y & 0xffff0000u);
    acc[4] += __uint_as_float(((unsigned)v.z) << 16);
    acc[5] += __uint_as_float(v.z & 0xffff0000u);
    acc[6] += __uint_as_float(((unsigned)v.w) << 16);
    acc[7] += __uint_as_float(v.w & 0xffff0000u);
}

// ---------------- CSR build: LDS counting sort ----------------
__global__ void k_zero(int* bcnt) {
    int i = threadIdx.x;
    if (i < NBKT) bcnt[i] = 0;
}

__launch_bounds__(512)
__global__ void k_bucket(const int* __restrict__ ei, int* __restrict__ bcnt,
                         int* __restrict__ bkt) {
    __shared__ int hist[NBKT], goff[NBKT], cur[NBKT];
    __shared__ int stage[TILE];
    int t = threadIdx.x;
    int e0 = blockIdx.x * TILE;
    int ecnt = min(TILE, NE - e0);
    for (int i = t; i < NBKT; i += 512) hist[i] = 0;
    __syncthreads();
    for (int i = t; i < ecnt; i += 512)
        atomicAdd(&hist[ei[NE + e0 + i] >> 8], 1);
    __syncthreads();
    if (t == 0) {
        int run = 0;
        for (int b = 0; b < NBKT; b++) { cur[b] = run; run += hist[b]; }
    }
    __syncthreads();
    for (int b = t; b < NBKT; b += 512)
        goff[b] = atomicAdd(&bcnt[b], hist[b]);
    __syncthreads();
    for (int i = t; i < ecnt; i += 512) {
        int c = ei[NE + e0 + i];
        int r = ei[e0 + i];
        int pos = atomicAdd(&cur[c >> 8], 1);
        stage[pos] = ((c & 255) << 17) | r;
    }
    __syncthreads();
    int wv = t >> 6, ln = t & 63;
    for (int b = wv; b < NBKT; b += 8) {
        int cnt = hist[b];
        int lo = cur[b] - cnt;
        int gb = b * BCAPB + goff[b];
        for (int i = ln; i < cnt; i += 64)
            bkt[gb + i] = stage[lo + i];
    }
}

__global__ void k_scanb(int* __restrict__ bcnt, int* __restrict__ bboff) {
    __shared__ int s[512];
    int t = threadIdx.x;
    int v = (t < NBKT) ? bcnt[t] : 0;
    s[t] = v;
    __syncthreads();
    for (int o = 1; o < 512; o <<= 1) {
        int add = (t >= o) ? s[t - o] : 0;
        __syncthreads();
        s[t] += add;
        __syncthreads();
    }
    if (t < NBKT) bboff[t] = s[t] - v;  // exclusive
}

__launch_bounds__(256)
__global__ void k_csr(const int* __restrict__ bcnt, const int* __restrict__ bboff,
                      const int* __restrict__ bkt, float* __restrict__ dinv,
                      int* __restrict__ cursor, int* __restrict__ eidx) {
    __shared__ int hist[256], loff[256], cur[256], sscan[256];
    __shared__ int stage[BCAPB];
    int t = threadIdx.x;
    int b = blockIdx.x;
    int cnt = bcnt[b];
    int base = bboff[b];
    const int* bp = bkt + b * BCAPB;
    hist[t] = 0;
    __syncthreads();
    for (int i = t; i < cnt; i += 256)
        atomicAdd(&hist[bp[i] >> 17], 1);
    __syncthreads();
    int n = b * 256 + t;
    int d = hist[t];
    if (n < NN) dinv[n] = rsqrtf((float)(d + 1));  // +1 self-loop
    sscan[t] = d;
    __syncthreads();
    for (int o = 1; o < 256; o <<= 1) {
        int add = (t >= o) ? sscan[t - o] : 0;
        __syncthreads();
        sscan[t] += add;
        __syncthreads();
    }
    loff[t] = sscan[t] - d;
    cur[t] = 0;
    if (n < NN) cursor[n] = base + sscan[t];  // rowoff[n+1]
    __syncthreads();
    for (int i = t; i < cnt; i += 256) {
        int v = bp[i];
        int pos = loff[v >> 17] + atomicAdd(&cur[v >> 17], 1);
        stage[pos] = v & 0x1FFFF;
    }
    __syncthreads();
    for (int i = t; i < cnt; i += 256)
        eidx[base + i] = stage[i];
}

// ---------------- GEMM1: h1' = bf16((x @ W1) * dinv[row]) ----------------
__launch_bounds__(256)
__global__ void k_gemm1(const float* __restrict__ x, const float* __restrict__ W1,
                        const float* __restrict__ dinv, u16* __restrict__ h1) {
    __shared__ float Xs[64][132];
    __shared__ float Ws[128][64];
    int t = threadIdx.x;
    int row0 = blockIdx.x * 64;

#pragma unroll
    for (int i = 0; i < 8; i++) {
        int idx4 = t + 256 * i;
        float4 v = ((const float4*)W1)[idx4];
        int k = idx4 >> 4;
        int c4 = (idx4 & 15) << 2;
        *(float4*)&Ws[k][c4] = v;
    }
#pragma unroll
    for (int i = 0; i < 8; i++) {
        int idx4 = t + 256 * i;
        int r = idx4 >> 5;
        int k4 = (idx4 & 31) << 2;
        int gr = row0 + r;
        if (gr >= NN) gr = NN - 1;
        float4 v = *(const float4*)&x[gr * F_IN + k4];
        *(float4*)&Xs[r][k4] = v;
    }
    __syncthreads();

    int tx = t & 15, ty = t >> 4;
    int cb = tx << 2, rb = ty << 2;
    float acc[4][4] = {};
#pragma unroll 2   // capped: full unroll spills (R1)
    for (int k = 0; k < F_IN; k += 4) {
        float4 xv[4], wv[4];
#pragma unroll
        for (int i = 0; i < 4; i++) xv[i] = *(const float4*)&Xs[rb + i][k];
#pragma unroll
        for (int kk = 0; kk < 4; kk++) wv[kk] = *(const float4*)&Ws[k + kk][cb];
#pragma unroll
        for (int i = 0; i < 4; i++) {
            const float* xp = (const float*)&xv[i];
#pragma unroll
            for (int kk = 0; kk < 4; kk++) {
                acc[i][0] += xp[kk] * wv[kk].x;
                acc[i][1] += xp[kk] * wv[kk].y;
                acc[i][2] += xp[kk] * wv[kk].z;
                acc[i][3] += xp[kk] * wv[kk].w;
            }
        }
    }
#pragma unroll
    for (int i = 0; i < 4; i++) {
        int gr = row0 + rb + i;
        if (gr < NN) {
            float dn = dinv[gr];
            ushort4 o;
            o.x = f2bf(acc[i][0] * dn); o.y = f2bf(acc[i][1] * dn);
            o.z = f2bf(acc[i][2] * dn); o.w = f2bf(acc[i][3] * dn);
            *(ushort4*)&h1[(size_t)gr * HID + cb] = o;
        }
    }
}

// ---------------- aggregation: reg-resident indices, pre-scaled rows ----------------
// One coalesced eidx load per wave; __shfl broadcasts indices; the row gather
// is the ONLY per-edge memory op (R9: eidx->dinv->row chain was latency-bound).
// out[n] = dinv[n]*(sum h'[src] + h'[n]); RELU_BIAS: relu(out+b)*dinv[n] (bf16)
template <bool RELU_BIAS, bool OUT_BF16>
__global__ void k_agg(const int* __restrict__ cursor, const int* __restrict__ eidx,
                      const float* __restrict__ dinv, const u16* __restrict__ h,
                      const float* __restrict__ bias, void* __restrict__ outp) {
    int lane = threadIdx.x & 63;
    int n = (blockIdx.x * blockDim.x + threadIdx.x) >> 6;
    if (n >= NN) return;
    int eg = lane >> 3;        // edge group 0..7
    int fo = (lane & 7) * 8;   // 8 bf16 per lane
    int end = cursor[n];
    int start = (n == 0) ? 0 : cursor[n - 1];
    int deg = end - start;

    float acc[8] = {}, acc2[8] = {};
    if (eg == 0) {  // self-loop row
        int4 hv = *(const int4*)&h[n * HID + fo];
        add8(hv, acc);
    }
    for (int c0 = 0; c0 < deg; c0 += 64) {
        int m = min(64, deg - c0);
        int sidx = (lane < m) ? eidx[start + c0 + lane] : 0;
        int kmax = (m + 7) >> 3;  // uniform across groups; guard e<m below
        int k = 0;
        for (; k + 2 <= kmax; k += 2) {
            int e0 = eg + (k << 3), e1 = e0 + 8;
            int s0 = __shfl(sidx, e0, 64);
            int s1 = __shfl(sidx, e1, 64);
            if (e0 < m) { int4 a = *(const int4*)&h[s0 * HID + fo]; add8(a, acc); }
            if (e1 < m) { int4 b = *(const int4*)&h[s1 * HID + fo]; add8(b, acc2); }
        }
        if (k < kmax) {
            int e0 = eg + (k << 3);
            int s0 = __shfl(sidx, e0, 64);
            if (e0 < m) { int4 a = *(const int4*)&h[s0 * HID + fo]; add8(a, acc); }
        }
    }
#pragma unroll
    for (int i = 0; i < 8; i++) acc[i] += acc2[i];

    // reduce across the 8 edge groups (lane bits 3,4,5)
#pragma unroll
    for (int o = 8; o <= 32; o <<= 1) {
#pragma unroll
        for (int i = 0; i < 8; i++) acc[i] += __shfl_xor(acc[i], o, 64);
    }
    if (eg == 0) {
        float dn = dinv[n];
        if (RELU_BIAS) {
#pragma unroll
            for (int i = 0; i < 8; i++)
                acc[i] = fmaxf(dn * acc[i] + bias[fo + i], 0.f) * dn;
        } else {
#pragma unroll
            for (int i = 0; i < 8; i++) acc[i] *= dn;
        }
        if (OUT_BF16) {
            int4 o;
            o.x = (int)f2bf(acc[0]) | ((int)f2bf(acc[1]) << 16);
            o.y = (int)f2bf(acc[2]) | ((int)f2bf(acc[3]) << 16);
            o.z = (int)f2bf(acc[4]) | ((int)f2bf(acc[5]) << 16);
            o.w = (int)f2bf(acc[6]) | ((int)f2bf(acc[7]) << 16);
            *(int4*)((u16*)outp + (size_t)n * HID + fo) = o;
        } else {
            float* op = (float*)outp + (size_t)n * HID + fo;
            *(float4*)op = make_float4(acc[0], acc[1], acc[2], acc[3]);
            *(float4*)(op + 4) = make_float4(acc[4], acc[5], acc[6], acc[7]);
        }
    }
}

// ---------------- GEMM2 + bias + log_softmax fused ----------------
__launch_bounds__(320)
__global__ void k_gemm2(const float* __restrict__ s_in, const float* __restrict__ W2,
                        const float* __restrict__ b2, float* __restrict__ outb) {
    __shared__ float As[128][68];   // staging; later reused as Os[40][132]
    __shared__ float Ws[64][40];
    __shared__ float rowm[128], rowls[128];
    int t = threadIdx.x;
    int row0 = blockIdx.x * 128;

    for (int i = t; i < 64 * 40; i += 320) Ws[i / 40][i % 40] = W2[i];

    for (int idx4 = t; idx4 < 2048; idx4 += 320) {
        int r = idx4 >> 4, k4 = (idx4 & 15) << 2;
        int gr = row0 + r;
        if (gr >= NN) gr = NN - 1;
        *(float4*)&As[r][k4] = *(const float4*)&s_in[(size_t)gr * HID + k4];
    }
    __syncthreads();

    int tx = t % 10, ty = t / 10;
    int cb = tx * 4, rb = ty * 4;
    float acc[4][4] = {};
#pragma unroll 2   // capped: full unroll spills (R1)
    for (int k = 0; k < HID; k += 4) {
        float4 xv[4], wv[4];
#pragma unroll
        for (int i = 0; i < 4; i++) xv[i] = *(const float4*)&As[rb + i][k];
#pragma unroll
        for (int kk = 0; kk < 4; kk++) wv[kk] = *(const float4*)&Ws[k + kk][cb];
#pragma unroll
        for (int i = 0; i < 4; i++) {
            const float* xp = (const float*)&xv[i];
#pragma unroll
            for (int kk = 0; kk < 4; kk++) {
                acc[i][0] += xp[kk] * wv[kk].x;
                acc[i][1] += xp[kk] * wv[kk].y;
                acc[i][2] += xp[kk] * wv[kk].z;
                acc[i][3] += xp[kk] * wv[kk].w;
            }
        }
    }
    float4 bb = *(const float4*)&b2[cb];
#pragma unroll
    for (int i = 0; i < 4; i++) {
        acc[i][0] += bb.x; acc[i][1] += bb.y;
        acc[i][2] += bb.z; acc[i][3] += bb.w;
    }

    // fused log_softmax over the 40 cols of each of the 128 rows
    __syncthreads();  // all As reads done; reuse as Os[40][132]
    float* Os = &As[0][0];
#pragma unroll
    for (int i = 0; i < 4; i++) {
        int row = rb + i;
        Os[(cb + 0) * 132 + row] = acc[i][0];
        Os[(cb + 1) * 132 + row] = acc[i][1];
        Os[(cb + 2) * 132 + row] = acc[i][2];
        Os[(cb + 3) * 132 + row] = acc[i][3];
    }
    __syncthreads();
    if (t < 128) {
        float m = -INFINITY;
        for (int c = 0; c < OUTF; c++) m = fmaxf(m, Os[c * 132 + t]);
        float sum = 0.f;
        for (int c = 0; c < OUTF; c++) sum += __expf(Os[c * 132 + t] - m);
        rowm[t] = m;
        rowls[t] = __logf(sum);
    }
    __syncthreads();
#pragma unroll
    for (int i = 0; i < 4; i++) {
        int row = rb + i;
        int gr = row0 + row;
        if (gr < NN) {
            float sh = rowm[row] + rowls[row];
            *(float4*)&outb[(size_t)gr * OUTF + cb] =
                make_float4(acc[i][0] - sh, acc[i][1] - sh,
                            acc[i][2] - sh, acc[i][3] - sh);
        }
    }
}

extern "C" void kernel_launch(void* const* d_in, const int* in_sizes, int n_in,
                              void* d_out, int out_size, void* d_ws, size_t ws_size,
                              hipStream_t stream) {
    const float* x  = (const float*)d_in[0];
    const int*   ei = (const int*)d_in[1];
    const float* W1 = (const float*)d_in[2];
    const float* b1 = (const float*)d_in[3];
    const float* W2 = (const float*)d_in[4];
    const float* b2 = (const float*)d_in[5];
    float* outb = (float*)d_out;

    // workspace layout (4B word units)
    float* dinv   = (float*)d_ws;                   // 100000
    int*   cursor = (int*)d_ws + 100000;            // 100000
    int*   bcnt   = (int*)d_ws + 200000;            // 512
    int*   bboff  = (int*)d_ws + 200512;            // 512
    int*   eidx   = (int*)d_ws + 201024;            // 1600000
    u16*   h1     = (u16*)((int*)d_ws + 1801024);   // 6.4M bf16 = 3.2M words
    u16*   r      = (u16*)((int*)d_ws + 5001024);   // 6.4M bf16 = 3.2M words
    float* s      = (float*)d_ws + 8201024;         // 6.4M fp32 words
    int*   bkt    = (int*)s;                        // NBKT*BCAPB = 2.0M words, dead before agg2

    k_zero<<<1, 512, 0, stream>>>(bcnt);
    k_bucket<<<NTILES, 512, 0, stream>>>(ei, bcnt, bkt);
    k_scanb<<<1, 512, 0, stream>>>(bcnt, bboff);
    k_csr<<<NBKT, 256, 0, stream>>>(bcnt, bboff, bkt, dinv, cursor, eidx);

    // h1' = bf16((x@W1)*dinv)
    k_gemm1<<<(NN + 63) / 64, 256, 0, stream>>>(x, W1, dinv, h1);
    // r' = bf16(relu(dinv*(sum h1') + b1) * dinv)
    k_agg<true, true><<<(NN * 64 + 255) / 256, 256, 0, stream>>>(cursor, eidx, dinv, h1, b1, r);
    // s = dinv*(sum r') (fp32)
    k_agg<false, false><<<(NN * 64 + 255) / 256, 256, 0, stream>>>(cursor, eidx, dinv, r, nullptr, s);
    // out = log_softmax(s @ W2 + b2)
    k_gemm2<<<(NN + 127) / 128, 320, 0, stream>>>(s, W2, b2, outb);
}